// Round 5
// baseline (182.476 us; speedup 1.0000x reference)
//
#include <hip/hip_runtime.h>

// GroupedConv2d via bf16 MFMA implicit GEMM — quad-plane LDS, 4-row chunks.
// G=8 groups x 32 gathered channels -> J=64, 3x3 pad=1.
// x[16,256,56,56] fp32 -> out[16,512,56,56] fp32.
//
// Block = (g, b, chunk of 4 output rows). 4 waves, wave jt owns 16 j's and
// computes all 14 pixel-tiles (2 bands). LDS pixel buffer is quad-plane:
// [row 0..5][kq 0..3][px 0..58] with 16 B per pixel-quad (8 channels);
// pixel p holds input col p-1 (px 0 / px 57 are the zero halos).
//  * reads: lane (n,kq) base = pixel colA, taps at compile-time immediates
//    (kh*SLOT + kw*16 B); quad index (3kq+n) mod 8 balanced -> conflict-free.
//    [round-4 bug fixed: base was pixel colA+1 -> shifted conv + read of
//     never-written px 58 (weight-stage garbage, absmax 4.6e37).]
//  * writes: task (q, 4-px group) -> 4x ds_write_b128, quad index
//    (4lr+3q+4p4+i) mod 8 balanced -> conflict-free (round-2's 32-way b32
//    staging writes were ~8M conflict cycles).
// 22.6 KB LDS; grid 1792 blocks; ~4 resident blocks/CU (register-capped).
// Weights (36.9 KB > buffer) staged in 2 passes through the pixel region.

#define NG 8
#define CPER 32
#define CIN 256
#define NJ 64
#define NB 16
#define NH 56
#define NW 56
#define HW (NH * NW)
#define PLANE_DW 236            // 59 px * 4 dwords (16 B per pixel-quad)
#define SLOT_DW 944             // 4 planes per row-slot
#define NSLOT 6
#define BUF_DW (NSLOT * SLOT_DW)   // 5664 dwords = 22656 B
#define NTASK 336               // 6 rows x 4 quads x 14 px-groups

typedef __attribute__((ext_vector_type(8))) short short8v;
typedef __attribute__((ext_vector_type(4))) float float4v;
typedef __attribute__((ext_vector_type(4))) unsigned int uint4v;

__device__ __forceinline__ unsigned bf16rne(float f) {
    unsigned u = __float_as_uint(f);
    return (u + 0x7FFFu + ((u >> 16) & 1u)) >> 16;
}

#define MFMA __builtin_amdgcn_mfma_f32_16x16x32_bf16

__global__ __launch_bounds__(256, 4)
void gconv_mfma(const float* __restrict__ x,
                const float* __restrict__ w,
                const float* __restrict__ bias,
                const int* __restrict__ arr,
                float* __restrict__ out) {
    __shared__ __align__(16) unsigned int smw[BUF_DW];
    unsigned short* sms = (unsigned short*)smw;

    const int tid   = threadIdx.x;
    const int chunk = blockIdx.x;      // 0..13 -> output rows [chunk*4, chunk*4+4)
    const int b     = blockIdx.y;
    const int g     = blockIdx.z;
    const int lane  = tid & 63;
    const int jt    = tid >> 6;        // wave id = j-tile (16 j's)
    const int n     = lane & 15;       // pixel-in-tile / j-in-tile
    const int kq    = lane >> 4;       // channel-quad (channels kq*8..kq*8+7)
    const int rbase = chunk * 4;

    // ---- stage weights in 2 passes (taps 0-4, then 5-8) through pixel LDS ----
    short8v A[9];
    {
        const float* wg = w + (size_t)g * (NJ * CPER * 9);
        #pragma unroll
        for (int pass = 0; pass < 2; ++pass) {
            const int t0 = pass ? 5 : 0;
            const int nt = pass ? 4 : 5;
            for (int e = tid; e < nt * 2048; e += 256) {
                int jc = e / nt, dt = e - jc * nt;
                sms[dt * 2048 + jc] = (unsigned short)bf16rne(wg[jc * 9 + t0 + dt]);
            }
            __syncthreads();
            const unsigned short* wl = sms + (jt * 16 + n) * CPER + kq * 8;
            #pragma unroll
            for (int dt = 0; dt < nt; ++dt)
                A[t0 + dt] = *(const short8v*)(wl + dt * 2048);
            __syncthreads();
        }
    }
    float4v binit;
    #pragma unroll
    for (int i = 0; i < 4; ++i) binit[i] = bias[g * NJ + jt * 16 + kq * 4 + i];

    // ---- zero halo pixels (px 0 and 57 of every plane): 48 b128 writes ----
    if (tid < 48) {
        int lr = tid >> 3, rm = tid & 7;
        int q = rm >> 1, px = (rm & 1) ? 57 : 0;
        uint4v z = {0u, 0u, 0u, 0u};
        *(uint4v*)(smw + lr * SLOT_DW + q * PLANE_DW + px * 4) = z;
    }

    // ---- stage 6 input rows (rbase-1 .. rbase+4), task = (quad, px-group) ----
    const float* xb = x + (size_t)b * (CIN * HW);
    const int* ag = arr + g * CPER;
    auto stage = [&](int t) {
        int q = t & 3, s = t >> 2;
        int p4 = s % 14, lr = s / 14;
        int irow = rbase - 1 + lr;
        bool v = (unsigned)irow < NH;
        const float* src = xb + irow * NW + 4 * p4;
        float4v vv[8];
        #pragma unroll
        for (int j = 0; j < 8; ++j) {
            float4v t0 = {0.f, 0.f, 0.f, 0.f};
            if (v) t0 = *(const float4v*)(src + ag[8 * q + j] * HW);
            vv[j] = t0;
        }
        unsigned int* d = smw + lr * SLOT_DW + q * PLANE_DW + (1 + 4 * p4) * 4;
        #pragma unroll
        for (int i = 0; i < 4; ++i) {
            uint4v val;
            #pragma unroll
            for (int dd = 0; dd < 4; ++dd)
                val[dd] = bf16rne(vv[2 * dd][i]) | (bf16rne(vv[2 * dd + 1][i]) << 16);
            *(uint4v*)(d + 4 * i) = val;
        }
    };
    stage(tid);
    if (tid < NTASK - 256) stage(tid + 256);
    __syncthreads();

    // ---- compute: wave jt does all 14 tiles (4 output rows), no barriers ----
    const int ob = ((b * (NG * NJ) + g * NJ + jt * 16 + kq * 4) * NH + rbase) * NW;
    int rl = 0, col = n;
    #pragma unroll
    for (int tp = 0; tp < 7; ++tp) {
        const int rlA = rl, colA = col;
        col += 16; if (col >= NW) { col -= NW; ++rl; }
        const int rlB = rl, colB = col;
        col += 16; if (col >= NW) { col -= NW; ++rl; }
        const unsigned int* pA = smw + rlA * SLOT_DW + kq * PLANE_DW + colA * 4;
        const unsigned int* pB = smw + rlB * SLOT_DW + kq * PLANE_DW + colB * 4;
        float4v a0 = binit, a1 = binit;
        #pragma unroll
        for (int kh = 0; kh < 3; ++kh)
            #pragma unroll
            for (int kw = 0; kw < 3; ++kw) {
                short8v x0 = *(const short8v*)(pA + kh * SLOT_DW + kw * 4);
                short8v y0 = *(const short8v*)(pB + kh * SLOT_DW + kw * 4);
                a0 = MFMA(A[kh * 3 + kw], x0, a0, 0, 0, 0);
                a1 = MFMA(A[kh * 3 + kw], y0, a1, 0, 0, 0);
            }
        const int oA = ob + rlA * NW + colA;
        const int oB = ob + rlB * NW + colB;
        #pragma unroll
        for (int i = 0; i < 4; ++i) {
            out[oA + i * HW] = a0[i];
            out[oB + i * HW] = a1[i];
        }
    }
}

extern "C" void kernel_launch(void* const* d_in, const int* in_sizes, int n_in,
                              void* d_out, int out_size, void* d_ws, size_t ws_size,
                              hipStream_t stream) {
    const float* x    = (const float*)d_in[0];
    const float* wght = (const float*)d_in[1];
    const float* bias = (const float*)d_in[2];
    const int*   arr  = (const int*)d_in[3];
    float* out = (float*)d_out;

    dim3 grid(14, NB, NG);   // 14 row-chunks x batch x group = 1792 blocks
    gconv_mfma<<<grid, 256, 0, stream>>>(x, wght, bias, arr, out);
}

// Round 6
// 169.285 us; speedup vs baseline: 1.0779x; 1.0779x over previous
//
#include <hip/hip_runtime.h>

// GroupedConv2d via bf16 MFMA implicit GEMM — global-weight-frag version.
// G=8 groups x 32 gathered channels -> J=64, 3x3 pad=1.
// x[16,256,56,56] fp32 -> out[16,512,56,56] fp32.
//
// Two kernels: (1) transpose_w: w[g][j][c][t] f32 -> wt[g][t][j][c] bf16
// (295 KB in d_ws). (2) main: block = (g, b, chunk of 4 output rows),
// 4 waves, wave jt owns 16 j's. A-fragments come straight from wt via 9
// coalesced global_load_dwordx4 (lane layout == fragment layout, L2-shared
// by the 224 blocks per g) -> NO weight LDS staging, NO weight barriers,
// and none of round-5's weight-path bank conflicts (b16 writes ~9-way on
// banks 0-6 + 64-B-stride frag reads 8-way on banks {0,16} ~= 5M cycles).
// LDS = quad-plane pixel buffer only: [row 0..5][kq][px 0..58], 16 B per
// pixel-quad; px p holds input col p-1 (px 0/57 = zero halo).
//  * staging writes: 4x ds_write_b128, quad idx (4lr+3q+4p4+i) mod 8
//    sweeps all 8 quad-banks -> conflict-free.
//  * compute reads: quad idx = 4(rl+kh)+3kq+n+kw mod 8 balanced -> free.
// 22.6 KB LDS, single __syncthreads, grid 1792; ~7 blocks/CU if VGPR<=64.

#define NG 8
#define CPER 32
#define CIN 256
#define NJ 64
#define NB 16
#define NH 56
#define NW 56
#define HW (NH * NW)
#define PLANE_DW 236            // 59 px * 4 dwords (16 B per pixel-quad)
#define SLOT_DW 944             // 4 planes per row-slot
#define NSLOT 6
#define BUF_DW (NSLOT * SLOT_DW)   // 5664 dwords = 22656 B
#define NTASK 336               // 6 rows x 4 quads x 14 px-groups

typedef __attribute__((ext_vector_type(8))) short short8v;
typedef __attribute__((ext_vector_type(4))) float float4v;
typedef __attribute__((ext_vector_type(4))) unsigned int uint4v;

__device__ __forceinline__ unsigned bf16rne(float f) {
    unsigned u = __float_as_uint(f);
    return (u + 0x7FFFu + ((u >> 16) & 1u)) >> 16;
}

#define MFMA __builtin_amdgcn_mfma_f32_16x16x32_bf16

// w[g][j][c][tap] f32 -> wt[g][tap][j][c] bf16.
// Writes: consecutive tid -> consecutive shorts (coalesced per tap).
__global__ __launch_bounds__(256)
void transpose_w(const float* __restrict__ w, unsigned short* __restrict__ wt) {
    const int idx = blockIdx.x * 256 + threadIdx.x;   // (g,j,c), 16384 total
    const float* src = w + (size_t)idx * 9;
    const int g = idx >> 11, jc = idx & 2047;
    #pragma unroll
    for (int t = 0; t < 9; ++t)
        wt[(g * 9 + t) * 2048 + jc] = (unsigned short)bf16rne(src[t]);
}

__global__ __launch_bounds__(256, 4)
void gconv_mfma(const float* __restrict__ x,
                const unsigned short* __restrict__ wt,
                const float* __restrict__ bias,
                const int* __restrict__ arr,
                float* __restrict__ out) {
    __shared__ __align__(16) unsigned int smw[BUF_DW];

    const int tid   = threadIdx.x;
    const int chunk = blockIdx.x;      // 0..13 -> output rows [chunk*4, chunk*4+4)
    const int b     = blockIdx.y;
    const int g     = blockIdx.z;
    const int lane  = tid & 63;
    const int jt    = tid >> 6;        // wave id = j-tile (16 j's)
    const int n     = lane & 15;       // pixel-in-tile / j-in-tile
    const int kq    = lane >> 4;       // channel-quad (channels kq*8..kq*8+7)
    const int rbase = chunk * 4;

    // ---- A-fragments: 9 coalesced 16-B loads from pre-transposed weights ----
    short8v A[9];
    {
        const unsigned short* wl =
            wt + (size_t)(g * 9) * 2048 + (jt * 16 + n) * CPER + kq * 8;
        #pragma unroll
        for (int t = 0; t < 9; ++t)
            A[t] = *(const short8v*)(wl + t * 2048);
    }
    float4v binit;
    #pragma unroll
    for (int i = 0; i < 4; ++i) binit[i] = bias[g * NJ + jt * 16 + kq * 4 + i];

    // ---- zero halo pixels (px 0 and 57 of every plane): 48 b128 writes ----
    if (tid < 48) {
        int lr = tid >> 3, rm = tid & 7;
        int q = rm >> 1, px = (rm & 1) ? 57 : 0;
        uint4v z = {0u, 0u, 0u, 0u};
        *(uint4v*)(smw + lr * SLOT_DW + q * PLANE_DW + px * 4) = z;
    }

    // ---- stage 6 input rows (rbase-1 .. rbase+4), task = (quad, px-group) ----
    const float* xb = x + (size_t)b * (CIN * HW);
    const int* ag = arr + g * CPER;
    auto stage = [&](int t) {
        int q = t & 3, s = t >> 2;
        int p4 = s % 14, lr = s / 14;
        int irow = rbase - 1 + lr;
        bool v = (unsigned)irow < NH;
        const float* src = xb + irow * NW + 4 * p4;
        float4v vv[8];
        #pragma unroll
        for (int j = 0; j < 8; ++j) {
            float4v t0 = {0.f, 0.f, 0.f, 0.f};
            if (v) t0 = *(const float4v*)(src + ag[8 * q + j] * HW);
            vv[j] = t0;
        }
        unsigned int* d = smw + lr * SLOT_DW + q * PLANE_DW + (1 + 4 * p4) * 4;
        #pragma unroll
        for (int i = 0; i < 4; ++i) {
            uint4v val;
            #pragma unroll
            for (int dd = 0; dd < 4; ++dd)
                val[dd] = bf16rne(vv[2 * dd][i]) | (bf16rne(vv[2 * dd + 1][i]) << 16);
            *(uint4v*)(d + 4 * i) = val;
        }
    };
    stage(tid);
    if (tid < NTASK - 256) stage(tid + 256);
    __syncthreads();

    // ---- compute: wave jt does all 14 tiles (4 output rows), no barriers ----
    const int ob = ((b * (NG * NJ) + g * NJ + jt * 16 + kq * 4) * NH + rbase) * NW;
    int rl = 0, col = n;
    #pragma unroll
    for (int tp = 0; tp < 7; ++tp) {
        const int rlA = rl, colA = col;
        col += 16; if (col >= NW) { col -= NW; ++rl; }
        const int rlB = rl, colB = col;
        col += 16; if (col >= NW) { col -= NW; ++rl; }
        const unsigned int* pA = smw + rlA * SLOT_DW + kq * PLANE_DW + colA * 4;
        const unsigned int* pB = smw + rlB * SLOT_DW + kq * PLANE_DW + colB * 4;
        float4v a0 = binit, a1 = binit;
        #pragma unroll
        for (int kh = 0; kh < 3; ++kh)
            #pragma unroll
            for (int kw = 0; kw < 3; ++kw) {
                short8v x0 = *(const short8v*)(pA + kh * SLOT_DW + kw * 4);
                short8v y0 = *(const short8v*)(pB + kh * SLOT_DW + kw * 4);
                a0 = MFMA(A[kh * 3 + kw], x0, a0, 0, 0, 0);
                a1 = MFMA(A[kh * 3 + kw], y0, a1, 0, 0, 0);
            }
        const int oA = ob + rlA * NW + colA;
        const int oB = ob + rlB * NW + colB;
        #pragma unroll
        for (int i = 0; i < 4; ++i) {
            out[oA + i * HW] = a0[i];
            out[oB + i * HW] = a1[i];
        }
    }
}

extern "C" void kernel_launch(void* const* d_in, const int* in_sizes, int n_in,
                              void* d_out, int out_size, void* d_ws, size_t ws_size,
                              hipStream_t stream) {
    const float* x    = (const float*)d_in[0];
    const float* wght = (const float*)d_in[1];
    const float* bias = (const float*)d_in[2];
    const int*   arr  = (const int*)d_in[3];
    float* out = (float*)d_out;
    unsigned short* wtp = (unsigned short*)d_ws;   // needs 294912 B

    transpose_w<<<dim3(64), 256, 0, stream>>>(wght, wtp);
    dim3 grid(14, NB, NG);   // 14 row-chunks x batch x group = 1792 blocks
    gconv_mfma<<<grid, 256, 0, stream>>>(x, wtp, bias, arr, out);
}